// Round 1
// baseline (392.663 us; speedup 1.0000x reference)
//
#include <hip/hip_runtime.h>
#include <math.h>

#define BS   8
#define CLS  4
#define CCH  256
#define HH   128
#define WW   128
#define HWSZ (HH * WW)   // 16384
#define LL   19
#define TKK  256
#define MHH  64
#define MWW  64

// ---------------------------------------------------------------------------
// Kernel 1: token projections (tiny)
//   tq[b,l,t] = sum_c token[b,l,c] * W2[t,c]
//   t3[b,l,o] = sum_t token[b,l,t] * W3[o,t] + b3[o]
// grid = BS*LL blocks, 256 threads (thread = t / o)
// ---------------------------------------------------------------------------
__global__ __launch_bounds__(256) void k_tok(
    const float* __restrict__ token, const float* __restrict__ W2,
    const float* __restrict__ W3, const float* __restrict__ b3,
    float* __restrict__ tq, float* __restrict__ t3g) {
  __shared__ float tok_s[TKK];
  const int bl = blockIdx.x;
  const int t  = threadIdx.x;
  tok_s[t] = token[bl * TKK + t];
  __syncthreads();
  const float4* w2r = (const float4*)(W2 + (size_t)t * TKK);
  const float4* w3r = (const float4*)(W3 + (size_t)t * TKK);
  float a2 = 0.f, a3 = 0.f;
#pragma unroll 8
  for (int i = 0; i < TKK / 4; ++i) {
    float4 x = w2r[i];
    float4 y = w3r[i];
    const float* ts = &tok_s[4 * i];
    a2 += x.x * ts[0] + x.y * ts[1] + x.z * ts[2] + x.w * ts[3];
    a3 += y.x * ts[0] + y.y * ts[1] + y.z * ts[2] + y.w * ts[3];
  }
  tq[bl * TKK + t]  = a2;
  t3g[bl * TKK + t] = a3 + b3[t];
}

// ---------------------------------------------------------------------------
// Kernel 2: u[b,l,c] = (1/64) * sum_t W1[t,c] * tq[b,l,t]
//   (1/64 folds the cls-mean 1/4 and the softmax scale 1/sqrt(256)=1/16)
// grid = BS*LL blocks, 256 threads (thread = c); W1 reads coalesced.
// ---------------------------------------------------------------------------
__global__ __launch_bounds__(256) void k_u(
    const float* __restrict__ tq, const float* __restrict__ W1,
    float* __restrict__ u) {
  __shared__ float tq_s[TKK];
  const int bl = blockIdx.x;
  const int c  = threadIdx.x;
  tq_s[c] = tq[bl * TKK + c];
  __syncthreads();
  float a0 = 0.f, a1 = 0.f, a2 = 0.f, a3 = 0.f;
#pragma unroll 4
  for (int t = 0; t < TKK; t += 4) {
    a0 += W1[(t + 0) * CCH + c] * tq_s[t + 0];
    a1 += W1[(t + 1) * CCH + c] * tq_s[t + 1];
    a2 += W1[(t + 2) * CCH + c] * tq_s[t + 2];
    a3 += W1[(t + 3) * CCH + c] * tq_s[t + 3];
  }
  u[bl * CCH + c] = (a0 + a1 + a2 + a3) * (1.0f / 64.0f);
}

// ---------------------------------------------------------------------------
// Main fused kernel. block = (b, 64-pixel tile). 256 threads = 4 waves,
// wave wv owns channel slice c in [wv*64, wv*64+64).
//   phase 1+2: q[pix,c] = sum_cl fea[(4b+cl)%8, c, n] * mask_up  (on the fly)
//              facc[l] += q * u[b,l,c]            (u broadcast from LDS, b128)
//   reduce partials across waves -> softmax over l (with a!=0 zeroing)
//   phase 4:   out[b,o,n] = sum_l p[l]*t3[b,l,o] + fea[b,o,n]
// LDS: u_s 19456 + t3_s 20480 + part_s 19456 + p_s 4864 = 64256 B -> 2 blk/CU
// ---------------------------------------------------------------------------
__global__ __launch_bounds__(256, 2) void k_main(
    const float* __restrict__ mask, const float* __restrict__ fea,
    const float* __restrict__ u, const float* __restrict__ t3g,
    float* __restrict__ out) {
  __shared__ float u_s[LL][CCH];       // [l][c], rows 1 KiB -> 16B aligned
  __shared__ float t3_s[CCH * 20];     // [o*20 + l], pad 19->20 for b128 reads
  __shared__ float part_s[4][LL][64];  // per-wave partial a
  __shared__ float p_s[LL][64];        // softmax probs, [l][pix] (lane-consec)

  const int blk  = blockIdx.x;
  const int b    = blk & 7;       // tile-major order: blocks sharing fea are adjacent
  const int tile = blk >> 3;      // 0..255
  const int h    = tile >> 1;
  const int w0   = (tile & 1) << 6;
  const int n0   = h * WW + w0;
  const int t    = threadIdx.x;
  const int pix  = t & 63;
  const int wv   = t >> 6;

  // stage u and t3 for this batch (coalesced global reads; odd-stride LDS writes)
#pragma unroll
  for (int l = 0; l < LL; ++l) {
    u_s[l][t]       = u[(b * LL + l) * CCH + t];
    t3_s[t * 20 + l] = t3g[(b * LL + l) * CCH + t];
  }

  // nearest-upsampled mask values for this pixel (out idx i -> in idx i/2)
  const int hrow = h >> 1;
  const int wcol = (w0 + pix) >> 1;
  float m0 = mask[(((size_t)(b * CLS + 0)) * MHH + hrow) * MWW + wcol];
  float m1 = mask[(((size_t)(b * CLS + 1)) * MHH + hrow) * MWW + wcol];
  float m2 = mask[(((size_t)(b * CLS + 2)) * MHH + hrow) * MWW + wcol];
  float m3 = mask[(((size_t)(b * CLS + 3)) * MHH + hrow) * MWW + wcol];

  __syncthreads();

  // fea batch indices: (4b+cl) % 8 == 4*(b&1) + cl
  const int f0 = (b & 1) * 4;
  const float* fp0 = fea + ((size_t)(f0 + 0) * CCH) * HWSZ + n0 + pix;
  const float* fp1 = fea + ((size_t)(f0 + 1) * CCH) * HWSZ + n0 + pix;
  const float* fp2 = fea + ((size_t)(f0 + 2) * CCH) * HWSZ + n0 + pix;
  const float* fp3 = fea + ((size_t)(f0 + 3) * CCH) * HWSZ + n0 + pix;

  float facc[LL];
#pragma unroll
  for (int l = 0; l < LL; ++l) facc[l] = 0.f;

  const int c0 = wv * 64;
#pragma unroll 1
  for (int cc = 0; cc < 64; cc += 16) {
    float q[16];
#pragma unroll
    for (int j = 0; j < 16; ++j) {
      const size_t off = (size_t)(c0 + cc + j) * HWSZ;
      q[j] = fp0[off] * m0 + fp1[off] * m1 + fp2[off] * m2 + fp3[off] * m3;
    }
#pragma unroll
    for (int l = 0; l < LL; ++l) {
      const float4* ur = (const float4*)&u_s[l][c0 + cc];  // uniform addr -> broadcast
      float s = facc[l];
#pragma unroll
      for (int jj = 0; jj < 4; ++jj) {
        const float4 uu = ur[jj];
        s += q[4 * jj + 0] * uu.x + q[4 * jj + 1] * uu.y +
             q[4 * jj + 2] * uu.z + q[4 * jj + 3] * uu.w;
      }
      facc[l] = s;
    }
  }

#pragma unroll
  for (int l = 0; l < LL; ++l) part_s[wv][l][pix] = facc[l];
  __syncthreads();

  // softmax over l (wave 0 only; lane = pix). facc already == a_ref/16.
  if (t < 64) {
    float a[LL];
    float mx = -INFINITY;
#pragma unroll
    for (int l = 0; l < LL; ++l) {
      a[l] = part_s[0][l][t] + part_s[1][l][t] + part_s[2][l][t] + part_s[3][l][t];
      mx = fmaxf(mx, a[l]);
    }
    float e[LL];
    float sum = 0.f;
#pragma unroll
    for (int l = 0; l < LL; ++l) { e[l] = __expf(a[l] - mx); sum += e[l]; }
    const float inv = 1.0f / sum;
#pragma unroll
    for (int l = 0; l < LL; ++l)
      p_s[l][t] = (a[l] != 0.f) ? e[l] * inv : 0.f;  // replicate where(a!=0,...)
  }
  __syncthreads();

  float p[LL];
#pragma unroll
  for (int l = 0; l < LL; ++l) p[l] = p_s[l][pix];  // lane-consecutive, free

  // phase 4: wave wv handles o in [wv*64, wv*64+64); coalesced fea/out access
  const int ob = wv * 64;
#pragma unroll 2
  for (int i = 0; i < 64; ++i) {
    const int o = ob + i;
    const float4* tr = (const float4*)&t3_s[o * 20];  // uniform addr broadcast
    float tv[20];
#pragma unroll
    for (int jj = 0; jj < 5; ++jj) {
      const float4 x = tr[jj];
      tv[4 * jj + 0] = x.x; tv[4 * jj + 1] = x.y;
      tv[4 * jj + 2] = x.z; tv[4 * jj + 3] = x.w;
    }
    float s = 0.f;
#pragma unroll
    for (int l = 0; l < LL; ++l) s += p[l] * tv[l];
    const size_t off = ((size_t)(b * CCH + o)) * HWSZ + n0 + pix;
    out[off] = s + fea[off];
  }
}

// ---------------------------------------------------------------------------
extern "C" void kernel_launch(void* const* d_in, const int* in_sizes, int n_in,
                              void* d_out, int out_size, void* d_ws, size_t ws_size,
                              hipStream_t stream) {
  (void)in_sizes; (void)n_in; (void)out_size; (void)ws_size;
  const float* mask  = (const float*)d_in[0];
  const float* fea   = (const float*)d_in[1];
  const float* token = (const float*)d_in[2];
  const float* W1    = (const float*)d_in[3];
  const float* W2    = (const float*)d_in[4];
  const float* W3    = (const float*)d_in[5];
  const float* b3    = (const float*)d_in[6];
  float* out = (float*)d_out;

  float* tq = (float*)d_ws;                 // BS*LL*TKK floats
  float* u  = tq + BS * LL * TKK;           // BS*LL*CCH floats
  float* t3 = u + BS * LL * CCH;            // BS*LL*CCH floats (< 512 KiB total)

  k_tok<<<BS * LL, 256, 0, stream>>>(token, W2, W3, b3, tq, t3);
  k_u<<<BS * LL, 256, 0, stream>>>(tq, W1, u);
  k_main<<<(HWSZ / 64) * BS, 256, 0, stream>>>(mask, fea, u, t3, out);
}